// Round 1
// baseline (1461.834 us; speedup 1.0000x reference)
//
#include <hip/hip_runtime.h>
#include <cstddef>
#include <cstdint>

#define B_ 64
#define S_ 4096
#define D_ 1024
#define CHUNKS 16
#define ROWS (S_ / CHUNKS) /* 256 rows per chunk */

// ---------------------------------------------------------------------------
// Small GEMM: C[b,i] = act( sum_d A1[b,d]*W1[i,d] (+ sum_d A2[b,d]*W2[i,d]) )
// A*: [64,1024] row-major, W*: [1024,1024] row-major (we need A @ W^T).
// grid = 256 blocks (4 output columns each), block = 256 threads (1 out/thread)
// ---------------------------------------------------------------------------
__global__ __launch_bounds__(256) void small_gemm(
    const float* __restrict__ A1, const float* __restrict__ W1,
    const float* __restrict__ A2, const float* __restrict__ W2,
    float* __restrict__ C, int do_tanh)
{
    int t = threadIdx.x;
    int i = blockIdx.x * 4 + (t & 3);
    int b = t >> 2;

    const float4* A14 = (const float4*)(A1 + (size_t)b * D_);
    const float4* W14 = (const float4*)(W1 + (size_t)i * D_);
    float acc = 0.f;
#pragma unroll 4
    for (int k = 0; k < D_ / 4; ++k) {
        float4 a = A14[k];
        float4 w = W14[k];
        acc += a.x * w.x + a.y * w.y + a.z * w.z + a.w * w.w;
    }
    if (A2 != nullptr) {
        const float4* A24 = (const float4*)(A2 + (size_t)b * D_);
        const float4* W24 = (const float4*)(W2 + (size_t)i * D_);
#pragma unroll 4
        for (int k = 0; k < D_ / 4; ++k) {
            float4 a = A24[k];
            float4 w = W24[k];
            acc += a.x * w.x + a.y * w.y + a.z * w.z + a.w * w.w;
        }
    }
    if (do_tanh) acc = tanhf(acc);
    C[(size_t)b * D_ + i] = acc;
}

// ---------------------------------------------------------------------------
// Pass 1: fused scores + online-softmax weighted accumulation.
// grid = (CHUNKS, B), block = 256. Thread t owns d = 4t..4t+3.
// Writes: raw masked scores -> align_out, per-chunk (m, l, acc[D]) partials.
// Context is read exactly once from HBM.
// ---------------------------------------------------------------------------
__global__ __launch_bounds__(256) void pass1(
    const float* __restrict__ ctx,   // [B,S,D]
    const int* __restrict__ mask,    // [B,S]
    const float* __restrict__ q,     // [B,D]
    float* __restrict__ align_out,   // [B,S] raw masked scores
    float* __restrict__ pm,          // [B*CHUNKS]
    float* __restrict__ pl,          // [B*CHUNKS]
    float* __restrict__ pacc)        // [B*CHUNKS, D]
{
    int b = blockIdx.y, c = blockIdx.x, t = threadIdx.x;
    int wave = t >> 6, lane = t & 63;

    __shared__ float4 qs[256];
    __shared__ float red[2][4][4]; // [buf][wave][row]

    qs[t] = ((const float4*)(q + (size_t)b * D_))[t];
    __syncthreads();
    float4 qv = qs[t];

    const float* cb = ctx + (size_t)b * S_ * D_ + (size_t)c * ROWS * D_;
    const int* mb = mask + (size_t)b * S_ + c * ROWS;
    float* ab = align_out + (size_t)b * S_ + c * ROWS;

    float m = -1e30f, l = 0.f;
    float a0 = 0.f, a1 = 0.f, a2 = 0.f, a3 = 0.f;

    for (int r0 = 0; r0 < ROWS; r0 += 4) {
        int buf = (r0 >> 2) & 1;
        float4 v0 = ((const float4*)(cb + (size_t)(r0 + 0) * D_))[t];
        float4 v1 = ((const float4*)(cb + (size_t)(r0 + 1) * D_))[t];
        float4 v2 = ((const float4*)(cb + (size_t)(r0 + 2) * D_))[t];
        float4 v3 = ((const float4*)(cb + (size_t)(r0 + 3) * D_))[t];

        float p0 = v0.x * qv.x + v0.y * qv.y + v0.z * qv.z + v0.w * qv.w;
        float p1 = v1.x * qv.x + v1.y * qv.y + v1.z * qv.z + v1.w * qv.w;
        float p2 = v2.x * qv.x + v2.y * qv.y + v2.z * qv.z + v2.w * qv.w;
        float p3 = v3.x * qv.x + v3.y * qv.y + v3.z * qv.z + v3.w * qv.w;

#pragma unroll
        for (int off = 32; off > 0; off >>= 1) {
            p0 += __shfl_down(p0, off);
            p1 += __shfl_down(p1, off);
            p2 += __shfl_down(p2, off);
            p3 += __shfl_down(p3, off);
        }
        if (lane == 0) {
            red[buf][wave][0] = p0;
            red[buf][wave][1] = p1;
            red[buf][wave][2] = p2;
            red[buf][wave][3] = p3;
        }
        __syncthreads();

        float s0 = red[buf][0][0] + red[buf][1][0] + red[buf][2][0] + red[buf][3][0];
        float s1 = red[buf][0][1] + red[buf][1][1] + red[buf][2][1] + red[buf][3][1];
        float s2 = red[buf][0][2] + red[buf][1][2] + red[buf][2][2] + red[buf][3][2];
        float s3 = red[buf][0][3] + red[buf][1][3] + red[buf][2][3] + red[buf][3][3];

        int m0 = mb[r0 + 0], m1 = mb[r0 + 1], m2 = mb[r0 + 2], m3 = mb[r0 + 3];
        s0 = m0 ? s0 : -1e30f;
        s1 = m1 ? s1 : -1e30f;
        s2 = m2 ? s2 : -1e30f;
        s3 = m3 ? s3 : -1e30f;

        if (t == 0) {
            ab[r0 + 0] = s0;
            ab[r0 + 1] = s1;
            ab[r0 + 2] = s2;
            ab[r0 + 3] = s3;
        }

        float nm = fmaxf(m, fmaxf(fmaxf(s0, s1), fmaxf(s2, s3)));
        float alpha = expf(m - nm); // m==-1e30 & nm real -> expf(-1e30)=0; both -1e30 -> 1
        float e0 = (s0 <= -1e29f) ? 0.f : expf(s0 - nm);
        float e1 = (s1 <= -1e29f) ? 0.f : expf(s1 - nm);
        float e2 = (s2 <= -1e29f) ? 0.f : expf(s2 - nm);
        float e3 = (s3 <= -1e29f) ? 0.f : expf(s3 - nm);

        l = l * alpha + (e0 + e1 + e2 + e3);
        a0 = a0 * alpha + e0 * v0.x + e1 * v1.x + e2 * v2.x + e3 * v3.x;
        a1 = a1 * alpha + e0 * v0.y + e1 * v1.y + e2 * v2.y + e3 * v3.y;
        a2 = a2 * alpha + e0 * v0.z + e1 * v1.z + e2 * v2.z + e3 * v3.z;
        a3 = a3 * alpha + e0 * v0.w + e1 * v1.w + e2 * v2.w + e3 * v3.w;
        m = nm;
    }

    int idx = b * CHUNKS + c;
    if (t == 0) {
        pm[idx] = m;
        pl[idx] = l;
    }
    float4 av;
    av.x = a0; av.y = a1; av.z = a2; av.w = a3;
    ((float4*)(pacc + (size_t)idx * D_))[t] = av;
}

// ---------------------------------------------------------------------------
// Combine chunk partials: wc[b,d] = sum_c acc_c[d]*exp(m_c-m)/l ; store (m,l).
// grid = B, block = 256 (thread t owns d = 4t..4t+3)
// ---------------------------------------------------------------------------
__global__ __launch_bounds__(256) void combine(
    const float* __restrict__ pm, const float* __restrict__ pl,
    const float* __restrict__ pacc,
    float* __restrict__ wc, float* __restrict__ ml)
{
    int b = blockIdx.x, t = threadIdx.x;
    float m = -1e30f;
#pragma unroll
    for (int c = 0; c < CHUNKS; ++c) m = fmaxf(m, pm[b * CHUNKS + c]);
    float l = 0.f;
    float w[CHUNKS];
#pragma unroll
    for (int c = 0; c < CHUNKS; ++c) {
        w[c] = expf(pm[b * CHUNKS + c] - m);
        l += pl[b * CHUNKS + c] * w[c];
    }
    float inv = (l > 0.f) ? 1.f / l : 0.f;
    float ax = 0.f, ay = 0.f, az = 0.f, aw = 0.f;
#pragma unroll
    for (int c = 0; c < CHUNKS; ++c) {
        float4 a = ((const float4*)(pacc + (size_t)(b * CHUNKS + c) * D_))[t];
        ax += a.x * w[c];
        ay += a.y * w[c];
        az += a.z * w[c];
        aw += a.w * w[c];
    }
    float4 r;
    r.x = ax * inv; r.y = ay * inv; r.z = az * inv; r.w = aw * inv;
    ((float4*)(wc + (size_t)b * D_))[t] = r;
    if (t == 0) {
        ml[b * 2 + 0] = m;
        ml[b * 2 + 1] = l;
    }
}

// ---------------------------------------------------------------------------
// Rewrite raw scores -> softmax probabilities in place.
// ---------------------------------------------------------------------------
__global__ __launch_bounds__(256) void finalize_att(
    float* __restrict__ att, const float* __restrict__ ml)
{
    int idx = blockIdx.x * 256 + threadIdx.x;
    int b = idx >> 12; // / S_
    float s = att[idx];
    float m = ml[b * 2 + 0], l = ml[b * 2 + 1];
    float v = (s <= -1e29f || !(l > 0.f)) ? 0.f : expf(s - m) / l;
    att[idx] = v;
}

// ---------------------------------------------------------------------------
extern "C" void kernel_launch(void* const* d_in, const int* in_sizes, int n_in,
                              void* d_out, int out_size, void* d_ws, size_t ws_size,
                              hipStream_t stream)
{
    const float* query     = (const float*)d_in[0]; // [B,D]
    const float* ctx       = (const float*)d_in[1]; // [B,S,D]
    const int*   mask      = (const int*)d_in[2];   // [B,S]
    const float* W_align   = (const float*)d_in[3]; // [D,D]
    const float* W_context = (const float*)d_in[4]; // [D,D]
    const float* W_query   = (const float*)d_in[5]; // [D,D]

    float* out = (float*)d_out;        // [B,D]   (65536)
    float* att = out + B_ * D_;        // [B,S]   (262144)
    float* wc  = att + B_ * S_;        // [B,D]   (65536)

    float* ws    = (float*)d_ws;
    float* qproj = ws;                       // B*D      = 65536 floats
    float* pm    = qproj + B_ * D_;          // B*CHUNKS = 1024
    float* pl    = pm + B_ * CHUNKS;         // 1024
    float* ml    = pl + B_ * CHUNKS;         // 128
    float* pacc  = ml + 2 * B_;              // B*CHUNKS*D = 1M floats (4 MB)

    // K1: q = query @ W_align^T
    small_gemm<<<dim3(D_ / 4), 256, 0, stream>>>(query, W_align, nullptr, nullptr, qproj, 0);

    // K2: fused scores + online softmax accumulation (single context pass)
    pass1<<<dim3(CHUNKS, B_), 256, 0, stream>>>(ctx, mask, qproj, att, pm, pl, pacc);

    // K3: merge chunk partials -> weight_context + per-batch (m,l)
    combine<<<dim3(B_), 256, 0, stream>>>(pm, pl, pacc, wc, ml);

    // K4: scores -> attention probabilities
    finalize_att<<<dim3(B_ * S_ / 256), 256, 0, stream>>>(att, ml);

    // K5: out = tanh(wc @ W_context^T + query @ W_query^T)
    small_gemm<<<dim3(D_ / 4), 256, 0, stream>>>(wc, W_context, query, W_query, out, 1);
}